// Round 14
// baseline (169.506 us; speedup 1.0000x reference)
//
#include <hip/hip_runtime.h>
#include <hip/hip_bf16.h>

// BCNet fused pipeline, MI355X gfx950 — round 14.
// Algebraic fusion: q_ exists ONLY to make qw = sum_q relu(q@Wq^T+bq)*wh[q].
// K1 no longer writes q_ (7.3MB) — its epilogue atomicAdds wh-scaled values
// straight into qw[128,2048] (f32, zeroed via hipMemsetAsync each call).
// gemm256 reverted to the byte-exact R10 source (qw read from global), LDS
// exactly 128 KiB (R13 lesson: >128 KiB costs ~17%).
//   M0: memset qw = 0
//   C0: cvt_qw  q,Wq f32->bf16
//   K1f: blocks 0-223: GEMM -> atomic qw; blocks 224-511: cvt v,Wv,W2
//   K3: logits = relu(vb @ Wvb^T + bv) * qw[b,:] + bh   (256² 8-phase)
//   K4: out = logits @ W2b^T + b2                       (256² 8-phase)

typedef __attribute__((ext_vector_type(4))) float f32x4;
typedef __attribute__((ext_vector_type(8))) short short8;

__device__ __forceinline__ short f2bf(float f) {
    union { float f; unsigned u; } x; x.f = f;
    unsigned u = x.u;
    unsigned r = (u + 0x7FFFu + ((u >> 16) & 1u)) >> 16;   // RN-even
    return (short)(r & 0xFFFFu);
}
__device__ __forceinline__ float bf2f(short s) {
    union { unsigned u; float f; } x; x.u = ((unsigned)(unsigned short)s) << 16;
    return x.f;
}

__device__ __forceinline__ void gload_lds16(const short* g, short* l) {
    __builtin_amdgcn_global_load_lds(
        (const __attribute__((address_space(1))) unsigned int*)g,
        (__attribute__((address_space(3))) unsigned int*)l,
        16, 0, 0);
}

__device__ __forceinline__ void cvt_chunk(const float* __restrict__ src,
                                          short* __restrict__ dst, int i)
{
    f32x4 a = *(const f32x4*)&src[i];
    f32x4 b = *(const f32x4*)&src[i + 4];
    short8 s;
    #pragma unroll
    for (int j = 0; j < 4; ++j) { s[j] = f2bf(a[j]); s[4 + j] = f2bf(b[j]); }
    *(short8*)&dst[i] = s;
}

// ---------------- cvt of q, Wq (must precede K1) ----------------
#define Q_CH  229376                  // 1792*1024/8
#define QW_CH 262144                  // 2048*1024/8
__global__ __launch_bounds__(256)
void cvt_qw(const float* __restrict__ q,  short* __restrict__ qb,
            const float* __restrict__ Wq, short* __restrict__ Wqb)
{
    const int total = Q_CH + QW_CH;
    const int stride = gridDim.x * 256;
    for (int c = blockIdx.x * 256 + threadIdx.x; c < total; c += stride) {
        if (c < Q_CH) cvt_chunk(q, qb, c * 8);
        else          cvt_chunk(Wq, Wqb, (c - Q_CH) * 8);
    }
}

// ---------------- K1 fused: 128² BK=64 GEMM -> atomic qw (blocks 0..223) + cvt (224..511) ----------------
#define V_CH  1179648                 // 4608*2048/8
#define WV_CH 524288                  // 2048*2048/8
#define W2_CH 524288
__global__ __launch_bounds__(256)
void k1_fused(const short* __restrict__ Ab, const short* __restrict__ Bb,
              const float* __restrict__ bias, const float* __restrict__ wh,
              float* __restrict__ qw,
              const float* __restrict__ v,  short* __restrict__ vb,
              const float* __restrict__ Wv, short* __restrict__ Wvb,
              const float* __restrict__ W2, short* __restrict__ W2b)
{
    __shared__ short ldsA[128 * 64];
    __shared__ short ldsB[128 * 64];

    if (blockIdx.x >= 224) {
        const int total = V_CH + WV_CH + W2_CH;
        const int stride = 288 * 256;
        for (int c = (blockIdx.x - 224) * 256 + threadIdx.x; c < total; c += stride) {
            if      (c < V_CH)         cvt_chunk(v,  vb,  c * 8);
            else if (c < V_CH + WV_CH) cvt_chunk(Wv, Wvb, (c - V_CH) * 8);
            else                       cvt_chunk(W2, W2b, (c - V_CH - WV_CH) * 8);
        }
        return;
    }

    const int K = 1024;
    const int tid    = threadIdx.x;
    const int lane   = tid & 63;
    const int wid    = tid >> 6;
    const int wr     = wid >> 1;
    const int wc     = wid & 1;
    const int lrow   = lane & 15;
    const int lchunk = lane >> 4;

    const int row0 = (blockIdx.x % 14) * 128;
    const int col0 = (blockIdx.x / 14) * 128;

    const int s_r = lane >> 3;
    const int s_c = ((lane & 7) ^ s_r) * 8;

    f32x4 acc[4][4];
    #pragma unroll
    for (int i = 0; i < 4; ++i)
        #pragma unroll
        for (int j = 0; j < 4; ++j)
            acc[i][j] = (f32x4)0.0f;

    const int nk = K >> 6;

    for (int kt = 0; kt < nk; ++kt) {
        const int kc = kt * 64;
        if (kt) __syncthreads();
        #pragma unroll
        for (int i = 0; i < 4; ++i) {
            const int r = wid * 32 + i * 8 + s_r;
            gload_lds16(&Ab[(size_t)(row0 + r) * K + kc + s_c],
                        &ldsA[(wid * 32 + i * 8) * 64]);
            gload_lds16(&Bb[(size_t)(col0 + r) * K + kc + s_c],
                        &ldsB[(wid * 32 + i * 8) * 64]);
        }
        __syncthreads();

        short8 af[4][2], bfv[4][2];
        #pragma unroll
        for (int mi = 0; mi < 4; ++mi) {
            const int row = wr * 64 + mi * 16 + lrow;
            #pragma unroll
            for (int ks = 0; ks < 2; ++ks)
                af[mi][ks] = *(const short8*)((const char*)ldsA +
                    row * 128 + (((ks * 4 + lchunk) * 16) ^ ((row & 7) << 4)));
        }
        #pragma unroll
        for (int ni = 0; ni < 4; ++ni) {
            const int row = wc * 64 + ni * 16 + lrow;
            #pragma unroll
            for (int ks = 0; ks < 2; ++ks)
                bfv[ni][ks] = *(const short8*)((const char*)ldsB +
                    row * 128 + (((ks * 4 + lchunk) * 16) ^ ((row & 7) << 4)));
        }
        #pragma unroll
        for (int ks = 0; ks < 2; ++ks)
            #pragma unroll
            for (int mi = 0; mi < 4; ++mi)
                #pragma unroll
                for (int ni = 0; ni < 4; ++ni)
                    acc[mi][ni] = __builtin_amdgcn_mfma_f32_16x16x32_bf16(
                        af[mi][ks], bfv[ni][ks], acc[mi][ni], 0, 0, 0);
    }

    // epilogue: qw[b, col] += relu(acc + bq[col]) * wh[row % 14]  (f32 atomics)
    #pragma unroll
    for (int mi = 0; mi < 4; ++mi)
        #pragma unroll
        for (int ni = 0; ni < 4; ++ni)
            #pragma unroll
            for (int r = 0; r < 4; ++r) {
                const int row = row0 + wr * 64 + mi * 16 + lchunk * 4 + r;
                const int col = col0 + wc * 64 + ni * 16 + lrow;
                const float val = fmaxf(acc[mi][ni][r] + bias[col], 0.0f);
                atomicAdd(&qw[(row / 14) * 2048 + col], val * wh[row % 14]);
            }
}

// ---------------- 256² 8-phase pipelined GEMM (K3/K4) — R10 source, 128 KiB LDS ----------------
// EPI: 1 = relu(acc+bias[n]) * qw[row/36, n] + bh -> bf16
//      2 = acc + bias[n]                          -> f32
template<int EPI>
__global__ __launch_bounds__(512, 2)
void gemm256(const short* __restrict__ Ab, const short* __restrict__ Bb,
             const float* __restrict__ bias, const float* __restrict__ qw,
             const float* __restrict__ bh_p, void* __restrict__ Cp,
             int M, int N, int K)
{
    __shared__ short lds[2][4][128 * 64];   // [buf][Aq0,Aq1,Bq0,Bq1] = 128 KiB

    const int tid  = threadIdx.x;
    const int lane = tid & 63;
    const int w    = tid >> 6;     // 0..7
    const int wr   = w >> 2;       // 0..1
    const int wc   = w & 3;        // 0..3
    const int fr   = lane & 15;
    const int fc   = lane >> 4;

    const int row0 = blockIdx.x * 256;
    const int col0 = blockIdx.y * 256;

    const int sl_s = lane >> 3;                    // 0..7
    const int sl_c = ((lane & 7) ^ sl_s) * 8;      // pre-swizzled source col (shorts)

    const int nt = K >> 6;         // even, >= 4

    f32x4 acc[8][4];
    #pragma unroll
    for (int i = 0; i < 8; ++i)
        #pragma unroll
        for (int j = 0; j < 4; ++j)
            acc[i][j] = (f32x4)0.0f;

    auto stageA = [&](int t, int q) {
        #pragma unroll
        for (int i = 0; i < 2; ++i) {
            const int g  = w * 2 + i;                  // 0..15
            const int rl = g * 8 + sl_s;               // 0..127 unit row
            const int srow = row0 + (g >> 3) * 128 + q * 64 + (rl & 63);
            gload_lds16(&Ab[(size_t)srow * K + t * 64 + sl_c],
                        &lds[t & 1][q][g * 512]);
        }
    };
    auto stageB = [&](int t, int q) {
        #pragma unroll
        for (int i = 0; i < 2; ++i) {
            const int g  = w * 2 + i;
            const int rl = g * 8 + sl_s;
            const int srow = col0 + (rl >> 5) * 64 + q * 32 + (rl & 31);
            gload_lds16(&Bb[(size_t)srow * K + t * 64 + sl_c],
                        &lds[t & 1][2 + q][g * 512]);
        }
    };

    short8 A0[4][2], A1[4][2], B0[2][2], B1[2][2];

#define READA(T, MQ, DST)                                                       \
    _Pragma("unroll") for (int m_ = 0; m_ < 4; ++m_) {                          \
        const int rl_ = wr * 64 + m_ * 16 + fr;                                 \
        _Pragma("unroll") for (int k_ = 0; k_ < 2; ++k_)                        \
            DST[m_][k_] = *(const short8*)((const char*)&lds[(T) & 1][MQ][0]    \
                + rl_ * 128 + ((k_ * 64 + fc * 16) ^ ((rl_ & 7) << 4)));        \
    }
#define READB(T, NQ, DST)                                                       \
    _Pragma("unroll") for (int n_ = 0; n_ < 2; ++n_) {                          \
        const int rl_ = wc * 32 + n_ * 16 + fr;                                 \
        _Pragma("unroll") for (int k_ = 0; k_ < 2; ++k_)                        \
            DST[n_][k_] = *(const short8*)((const char*)&lds[(T) & 1][2 + (NQ)][0] \
                + rl_ * 128 + ((k_ * 64 + fc * 16) ^ ((rl_ & 7) << 4)));        \
    }
#define MFMAQ(MQ, NQ, ASET, BSET)                                               \
    _Pragma("unroll") for (int m_ = 0; m_ < 4; ++m_)                            \
      _Pragma("unroll") for (int n_ = 0; n_ < 2; ++n_)                          \
        _Pragma("unroll") for (int k_ = 0; k_ < 2; ++k_)                        \
          acc[(MQ) * 4 + m_][(NQ) * 2 + n_] =                                   \
              __builtin_amdgcn_mfma_f32_16x16x32_bf16(                          \
                  ASET[m_][k_], BSET[n_][k_], acc[(MQ) * 4 + m_][(NQ) * 2 + n_], 0, 0, 0);

#define BAR()   asm volatile("s_barrier" ::: "memory")
#define PRIO1() __builtin_amdgcn_s_setprio(1)
#define PRIO0() __builtin_amdgcn_s_setprio(0)
#define VM4()   asm volatile("s_waitcnt vmcnt(4)" ::: "memory")
#define VM0()   asm volatile("s_waitcnt vmcnt(0)" ::: "memory")

#define KITER(T0, T1, ST1, ST2, ST3, ST4, ST5, ST6, ST7, ST8, D4, D8)           \
  {                                                                             \
    READA(T0, 0, A0); READB(T0, 0, B0);                                         \
    PRIO1(); MFMAQ(0, 0, A0, B0); PRIO0();                                      \
    READB(T0, 1, B1); ST1; BAR();                                               \
    PRIO1(); MFMAQ(0, 1, A0, B1); PRIO0();                                      \
    READA(T0, 1, A1); ST2; BAR();                                               \
    PRIO1(); MFMAQ(1, 1, A1, B1); PRIO0();                                      \
    ST3; BAR();                                                                 \
    PRIO1(); MFMAQ(1, 0, A1, B0); PRIO0();                                      \
    ST4; D4; BAR();                                                             \
    READA(T1, 0, A0); READB(T1, 0, B0);                                         \
    PRIO1(); MFMAQ(0, 0, A0, B0); PRIO0();                                      \
    READB(T1, 1, B1); ST5; BAR();                                               \
    PRIO1(); MFMAQ(0, 1, A0, B1); PRIO0();                                      \
    READA(T1, 1, A1); ST6; BAR();                                               \
    PRIO1(); MFMAQ(1, 1, A1, B1); PRIO0();                                      \
    ST7; BAR();                                                                 \
    PRIO1(); MFMAQ(1, 0, A1, B0); PRIO0();                                      \
    ST8; D8; BAR();                                                             \
  }

    // prologue: T0 fully + Aq0(T1) + Bq1(T1); drain to T0-complete
    stageA(0, 0); stageB(0, 0); stageB(0, 1); stageA(0, 1);
    stageA(1, 0); stageB(1, 1);
    VM4();
    BAR();

    const int niter = (nt >> 1) - 1;
    for (int j = 0; j < niter; ++j) {
        const int t0 = 2 * j, t1 = 2 * j + 1;
        KITER(t0, t1,
              stageA(t1, 1),     stageB(t1, 0),
              stageA(t0 + 2, 0), stageB(t0 + 2, 1),
              stageA(t0 + 2, 1), stageB(t0 + 2, 0),
              stageA(t1 + 2, 0), stageB(t1 + 2, 1),
              VM4(), VM4());
    }
    // tail iteration
    {
        const int t0 = nt - 2, t1 = nt - 1;
        KITER(t0, t1,
              stageA(t1, 1), stageB(t1, 0),
              (void)0, (void)0, (void)0, (void)0, (void)0, (void)0,
              VM0(), (void)0);
    }

#undef KITER
#undef READA
#undef READB
#undef MFMAQ
#undef BAR
#undef PRIO1
#undef PRIO0
#undef VM4
#undef VM0

    // epilogue: C/D layout col = lane&15, row = (lane>>4)*4 + reg
    const float bhv = (EPI == 1) ? bh_p[0] : 0.0f;
    #pragma unroll
    for (int m = 0; m < 8; ++m) {
        #pragma unroll
        for (int n = 0; n < 4; ++n) {
            #pragma unroll
            for (int r = 0; r < 4; ++r) {
                const int row = row0 + wr * 128 + m * 16 + fc * 4 + r;
                const int col = col0 + wc * 64 + n * 16 + fr;
                float val = acc[m][n][r];
                if (EPI == 1) {
                    val = fmaxf(val + bias[col], 0.0f);
                    const int b = row / 36;
                    val = val * qw[b * 2048 + col] + bhv;
                    ((short*)Cp)[(size_t)row * N + col] = f2bf(val);
                } else {
                    ((float*)Cp)[(size_t)row * N + col] = val + bias[col];
                }
            }
        }
    }
}

extern "C" void kernel_launch(void* const* d_in, const int* in_sizes, int n_in,
                              void* d_out, int out_size, void* d_ws, size_t ws_size,
                              hipStream_t stream)
{
    const float* v  = (const float*)d_in[0];
    const float* q  = (const float*)d_in[1];
    const float* Wv = (const float*)d_in[2];
    const float* bv = (const float*)d_in[3];
    const float* Wq = (const float*)d_in[4];
    const float* bq = (const float*)d_in[5];
    const float* wh = (const float*)d_in[6];
    const float* bh = (const float*)d_in[7];
    const float* W2 = (const float*)d_in[8];
    const float* b2 = (const float*)d_in[9];
    float* out = (float*)d_out;

    char* ws = (char*)d_ws;
    short* vb     = (short*)(ws);                  // 4608*2048*2 = 18,874,368
    short* Wvb    = (short*)(ws + 18874368);       // 2048*2048*2 =  8,388,608
    short* W2b    = (short*)(ws + 27262976);       // 2048*2048*2 =  8,388,608
    short* qb     = (short*)(ws + 35651584);       // 1792*1024*2 =  3,670,016
    short* Wqb    = (short*)(ws + 39321600);       // 2048*1024*2 =  4,194,304
    float* qw     = (float*)(ws + 43515904);       // 128*2048*4  =  1,048,576
    short* logits = (short*)(ws + 44564480);       // 4608*2048*2 = 18,874,368
    // total: 63,438,848 B

    // M0: zero the qw accumulator (K1 atomicAdds into it every call)
    hipMemsetAsync(qw, 0, 128 * 2048 * sizeof(float), stream);

    // C0: convert q, Wq (needed by K1)
    cvt_qw<<<1024, 256, 0, stream>>>(q, qb, Wq, Wqb);

    // K1 fused: GEMM -> atomic qw (224 blocks) + cvt of v/Wv/W2 (288 blocks)
    k1_fused<<<512, 256, 0, stream>>>(qb, Wqb, bq, wh, qw,
                                      v, vb, Wv, Wvb, W2, W2b);

    // K3: logits = relu(vb @ Wvb^T + bv) * qw + bh
    gemm256<1><<<dim3(4608 / 256, 2048 / 256), 512, 0, stream>>>(
        vb, Wvb, bv, qw, bh, logits, 4608, 2048, 2048);

    // K4: out = logits @ W2b^T + b2
    gemm256<2><<<dim3(4608 / 256, 2048 / 256), 512, 0, stream>>>(
        logits, W2b, b2, nullptr, nullptr, out, 4608, 2048, 2048);
}

// Round 15
// 140.309 us; speedup vs baseline: 1.2081x; 1.2081x over previous
//
#include <hip/hip_runtime.h>
#include <hip/hip_bf16.h>

// BCNet fused pipeline, MI355X gfx950 — round 15 (consolidation).
// Best-proven assembly: R10 structure verbatim; cvt_qw widened to 2048 blocks.
//   C0: cvt_qw  q,Wq f32->bf16
//   K1f: blocks 0-223: q_ = relu(qb @ Wqb^T + bq); blocks 224-511: cvt v,Wv,W2
//   K2: qw[128,2048] = sum_q q_[b*14+q,:] * wh[q]
//   K3: logits = relu(vb @ Wvb^T + bv) * qw + bh       (256² 8-phase, 128 KiB LDS)
//   K4: out = logits @ W2b^T + b2                      (256² 8-phase)

typedef __attribute__((ext_vector_type(4))) float f32x4;
typedef __attribute__((ext_vector_type(8))) short short8;

__device__ __forceinline__ short f2bf(float f) {
    union { float f; unsigned u; } x; x.f = f;
    unsigned u = x.u;
    unsigned r = (u + 0x7FFFu + ((u >> 16) & 1u)) >> 16;   // RN-even
    return (short)(r & 0xFFFFu);
}
__device__ __forceinline__ float bf2f(short s) {
    union { unsigned u; float f; } x; x.u = ((unsigned)(unsigned short)s) << 16;
    return x.f;
}

__device__ __forceinline__ void gload_lds16(const short* g, short* l) {
    __builtin_amdgcn_global_load_lds(
        (const __attribute__((address_space(1))) unsigned int*)g,
        (__attribute__((address_space(3))) unsigned int*)l,
        16, 0, 0);
}

__device__ __forceinline__ void cvt_chunk(const float* __restrict__ src,
                                          short* __restrict__ dst, int i)
{
    f32x4 a = *(const f32x4*)&src[i];
    f32x4 b = *(const f32x4*)&src[i + 4];
    short8 s;
    #pragma unroll
    for (int j = 0; j < 4; ++j) { s[j] = f2bf(a[j]); s[4 + j] = f2bf(b[j]); }
    *(short8*)&dst[i] = s;
}

// ---------------- cvt of q, Wq (must precede K1) ----------------
#define Q_CH  229376                  // 1792*1024/8
#define QW_CH 262144                  // 2048*1024/8
__global__ __launch_bounds__(256)
void cvt_qw(const float* __restrict__ q,  short* __restrict__ qb,
            const float* __restrict__ Wq, short* __restrict__ Wqb)
{
    const int total = Q_CH + QW_CH;
    const int stride = gridDim.x * 256;
    for (int c = blockIdx.x * 256 + threadIdx.x; c < total; c += stride) {
        if (c < Q_CH) cvt_chunk(q, qb, c * 8);
        else          cvt_chunk(Wq, Wqb, (c - Q_CH) * 8);
    }
}

// ---------------- K1 fused: 128² BK=64 GEMM (blocks 0..223) + cvt (224..511) ----------------
// GEMM: q_[1792,2048] = relu(qb[1792,1024] @ Wqb[2048,1024]^T + bq) -> bf16
#define V_CH  1179648                 // 4608*2048/8
#define WV_CH 524288                  // 2048*2048/8
#define W2_CH 524288
__global__ __launch_bounds__(256)
void k1_fused(const short* __restrict__ Ab, const short* __restrict__ Bb,
              const float* __restrict__ bias, short* __restrict__ Cp,
              const float* __restrict__ v,  short* __restrict__ vb,
              const float* __restrict__ Wv, short* __restrict__ Wvb,
              const float* __restrict__ W2, short* __restrict__ W2b)
{
    __shared__ short ldsA[128 * 64];
    __shared__ short ldsB[128 * 64];

    if (blockIdx.x >= 224) {
        // ---- conversion path: v, Wv, W2 ----
        const int total = V_CH + WV_CH + W2_CH;          // 2,228,224 chunks
        const int stride = 288 * 256;
        for (int c = (blockIdx.x - 224) * 256 + threadIdx.x; c < total; c += stride) {
            if      (c < V_CH)         cvt_chunk(v,  vb,  c * 8);
            else if (c < V_CH + WV_CH) cvt_chunk(Wv, Wvb, (c - V_CH) * 8);
            else                       cvt_chunk(W2, W2b, (c - V_CH - WV_CH) * 8);
        }
        return;
    }

    // ---- GEMM path (proven gemm_bt128, M=1792 N=2048 K=1024) ----
    const int K = 1024, N = 2048;
    const int tid    = threadIdx.x;
    const int lane   = tid & 63;
    const int wid    = tid >> 6;
    const int wr     = wid >> 1;
    const int wc     = wid & 1;
    const int lrow   = lane & 15;
    const int lchunk = lane >> 4;

    const int row0 = (blockIdx.x % 14) * 128;
    const int col0 = (blockIdx.x / 14) * 128;

    const int s_r = lane >> 3;
    const int s_c = ((lane & 7) ^ s_r) * 8;

    f32x4 acc[4][4];
    #pragma unroll
    for (int i = 0; i < 4; ++i)
        #pragma unroll
        for (int j = 0; j < 4; ++j)
            acc[i][j] = (f32x4)0.0f;

    const int nk = K >> 6;

    for (int kt = 0; kt < nk; ++kt) {
        const int kc = kt * 64;
        if (kt) __syncthreads();
        #pragma unroll
        for (int i = 0; i < 4; ++i) {
            const int r = wid * 32 + i * 8 + s_r;
            gload_lds16(&Ab[(size_t)(row0 + r) * K + kc + s_c],
                        &ldsA[(wid * 32 + i * 8) * 64]);
            gload_lds16(&Bb[(size_t)(col0 + r) * K + kc + s_c],
                        &ldsB[(wid * 32 + i * 8) * 64]);
        }
        __syncthreads();

        short8 af[4][2], bfv[4][2];
        #pragma unroll
        for (int mi = 0; mi < 4; ++mi) {
            const int row = wr * 64 + mi * 16 + lrow;
            #pragma unroll
            for (int ks = 0; ks < 2; ++ks)
                af[mi][ks] = *(const short8*)((const char*)ldsA +
                    row * 128 + (((ks * 4 + lchunk) * 16) ^ ((row & 7) << 4)));
        }
        #pragma unroll
        for (int ni = 0; ni < 4; ++ni) {
            const int row = wc * 64 + ni * 16 + lrow;
            #pragma unroll
            for (int ks = 0; ks < 2; ++ks)
                bfv[ni][ks] = *(const short8*)((const char*)ldsB +
                    row * 128 + (((ks * 4 + lchunk) * 16) ^ ((row & 7) << 4)));
        }
        #pragma unroll
        for (int ks = 0; ks < 2; ++ks)
            #pragma unroll
            for (int mi = 0; mi < 4; ++mi)
                #pragma unroll
                for (int ni = 0; ni < 4; ++ni)
                    acc[mi][ni] = __builtin_amdgcn_mfma_f32_16x16x32_bf16(
                        af[mi][ks], bfv[ni][ks], acc[mi][ni], 0, 0, 0);
    }

    #pragma unroll
    for (int mi = 0; mi < 4; ++mi)
        #pragma unroll
        for (int ni = 0; ni < 4; ++ni)
            #pragma unroll
            for (int r = 0; r < 4; ++r) {
                const int row = row0 + wr * 64 + mi * 16 + lchunk * 4 + r;
                const int col = col0 + wc * 64 + ni * 16 + lrow;
                float val = fmaxf(acc[mi][ni][r] + bias[col], 0.0f);
                Cp[(size_t)row * N + col] = f2bf(val);
            }
}

// ---------------- 256² 8-phase pipelined GEMM (K3/K4) — R10 source, 128 KiB LDS ----------------
// EPI: 1 = relu(acc+bias[n]) * qw[row/36, n] + bh -> bf16
//      2 = acc + bias[n]                          -> f32
template<int EPI>
__global__ __launch_bounds__(512, 2)
void gemm256(const short* __restrict__ Ab, const short* __restrict__ Bb,
             const float* __restrict__ bias, const float* __restrict__ qw,
             const float* __restrict__ bh_p, void* __restrict__ Cp,
             int M, int N, int K)
{
    __shared__ short lds[2][4][128 * 64];   // [buf][Aq0,Aq1,Bq0,Bq1] = 128 KiB

    const int tid  = threadIdx.x;
    const int lane = tid & 63;
    const int w    = tid >> 6;     // 0..7
    const int wr   = w >> 2;       // 0..1
    const int wc   = w & 3;        // 0..3
    const int fr   = lane & 15;
    const int fc   = lane >> 4;

    const int row0 = blockIdx.x * 256;
    const int col0 = blockIdx.y * 256;

    const int sl_s = lane >> 3;                    // 0..7
    const int sl_c = ((lane & 7) ^ sl_s) * 8;      // pre-swizzled source col (shorts)

    const int nt = K >> 6;         // even, >= 4

    f32x4 acc[8][4];
    #pragma unroll
    for (int i = 0; i < 8; ++i)
        #pragma unroll
        for (int j = 0; j < 4; ++j)
            acc[i][j] = (f32x4)0.0f;

    auto stageA = [&](int t, int q) {
        #pragma unroll
        for (int i = 0; i < 2; ++i) {
            const int g  = w * 2 + i;                  // 0..15
            const int rl = g * 8 + sl_s;               // 0..127 unit row
            const int srow = row0 + (g >> 3) * 128 + q * 64 + (rl & 63);
            gload_lds16(&Ab[(size_t)srow * K + t * 64 + sl_c],
                        &lds[t & 1][q][g * 512]);
        }
    };
    auto stageB = [&](int t, int q) {
        #pragma unroll
        for (int i = 0; i < 2; ++i) {
            const int g  = w * 2 + i;
            const int rl = g * 8 + sl_s;
            const int srow = col0 + (rl >> 5) * 64 + q * 32 + (rl & 31);
            gload_lds16(&Bb[(size_t)srow * K + t * 64 + sl_c],
                        &lds[t & 1][2 + q][g * 512]);
        }
    };

    short8 A0[4][2], A1[4][2], B0[2][2], B1[2][2];

#define READA(T, MQ, DST)                                                       \
    _Pragma("unroll") for (int m_ = 0; m_ < 4; ++m_) {                          \
        const int rl_ = wr * 64 + m_ * 16 + fr;                                 \
        _Pragma("unroll") for (int k_ = 0; k_ < 2; ++k_)                        \
            DST[m_][k_] = *(const short8*)((const char*)&lds[(T) & 1][MQ][0]    \
                + rl_ * 128 + ((k_ * 64 + fc * 16) ^ ((rl_ & 7) << 4)));        \
    }
#define READB(T, NQ, DST)                                                       \
    _Pragma("unroll") for (int n_ = 0; n_ < 2; ++n_) {                          \
        const int rl_ = wc * 32 + n_ * 16 + fr;                                 \
        _Pragma("unroll") for (int k_ = 0; k_ < 2; ++k_)                        \
            DST[n_][k_] = *(const short8*)((const char*)&lds[(T) & 1][2 + (NQ)][0] \
                + rl_ * 128 + ((k_ * 64 + fc * 16) ^ ((rl_ & 7) << 4)));        \
    }
#define MFMAQ(MQ, NQ, ASET, BSET)                                               \
    _Pragma("unroll") for (int m_ = 0; m_ < 4; ++m_)                            \
      _Pragma("unroll") for (int n_ = 0; n_ < 2; ++n_)                          \
        _Pragma("unroll") for (int k_ = 0; k_ < 2; ++k_)                        \
          acc[(MQ) * 4 + m_][(NQ) * 2 + n_] =                                   \
              __builtin_amdgcn_mfma_f32_16x16x32_bf16(                          \
                  ASET[m_][k_], BSET[n_][k_], acc[(MQ) * 4 + m_][(NQ) * 2 + n_], 0, 0, 0);

#define BAR()   asm volatile("s_barrier" ::: "memory")
#define PRIO1() __builtin_amdgcn_s_setprio(1)
#define PRIO0() __builtin_amdgcn_s_setprio(0)
#define VM4()   asm volatile("s_waitcnt vmcnt(4)" ::: "memory")
#define VM0()   asm volatile("s_waitcnt vmcnt(0)" ::: "memory")

#define KITER(T0, T1, ST1, ST2, ST3, ST4, ST5, ST6, ST7, ST8, D4, D8)           \
  {                                                                             \
    READA(T0, 0, A0); READB(T0, 0, B0);                                         \
    PRIO1(); MFMAQ(0, 0, A0, B0); PRIO0();                                      \
    READB(T0, 1, B1); ST1; BAR();                                               \
    PRIO1(); MFMAQ(0, 1, A0, B1); PRIO0();                                      \
    READA(T0, 1, A1); ST2; BAR();                                               \
    PRIO1(); MFMAQ(1, 1, A1, B1); PRIO0();                                      \
    ST3; BAR();                                                                 \
    PRIO1(); MFMAQ(1, 0, A1, B0); PRIO0();                                      \
    ST4; D4; BAR();                                                             \
    READA(T1, 0, A0); READB(T1, 0, B0);                                         \
    PRIO1(); MFMAQ(0, 0, A0, B0); PRIO0();                                      \
    READB(T1, 1, B1); ST5; BAR();                                               \
    PRIO1(); MFMAQ(0, 1, A0, B1); PRIO0();                                      \
    READA(T1, 1, A1); ST6; BAR();                                               \
    PRIO1(); MFMAQ(1, 1, A1, B1); PRIO0();                                      \
    ST7; BAR();                                                                 \
    PRIO1(); MFMAQ(1, 0, A1, B0); PRIO0();                                      \
    ST8; D8; BAR();                                                             \
  }

    // prologue: T0 fully + Aq0(T1) + Bq1(T1); drain to T0-complete
    stageA(0, 0); stageB(0, 0); stageB(0, 1); stageA(0, 1);
    stageA(1, 0); stageB(1, 1);
    VM4();
    BAR();

    const int niter = (nt >> 1) - 1;
    for (int j = 0; j < niter; ++j) {
        const int t0 = 2 * j, t1 = 2 * j + 1;
        KITER(t0, t1,
              stageA(t1, 1),     stageB(t1, 0),
              stageA(t0 + 2, 0), stageB(t0 + 2, 1),
              stageA(t0 + 2, 1), stageB(t0 + 2, 0),
              stageA(t1 + 2, 0), stageB(t1 + 2, 1),
              VM4(), VM4());
    }
    // tail iteration
    {
        const int t0 = nt - 2, t1 = nt - 1;
        KITER(t0, t1,
              stageA(t1, 1), stageB(t1, 0),
              (void)0, (void)0, (void)0, (void)0, (void)0, (void)0,
              VM0(), (void)0);
    }

#undef KITER
#undef READA
#undef READB
#undef MFMAQ
#undef BAR
#undef PRIO1
#undef PRIO0
#undef VM4
#undef VM0

    // epilogue: C/D layout col = lane&15, row = (lane>>4)*4 + reg
    const float bhv = (EPI == 1) ? bh_p[0] : 0.0f;
    #pragma unroll
    for (int m = 0; m < 8; ++m) {
        #pragma unroll
        for (int n = 0; n < 4; ++n) {
            #pragma unroll
            for (int r = 0; r < 4; ++r) {
                const int row = row0 + wr * 128 + m * 16 + fc * 4 + r;
                const int col = col0 + wc * 64 + n * 16 + fr;
                float val = acc[m][n][r];
                if (EPI == 1) {
                    val = fmaxf(val + bias[col], 0.0f);
                    const int b = row / 36;
                    val = val * qw[b * 2048 + col] + bhv;
                    ((short*)Cp)[(size_t)row * N + col] = f2bf(val);
                } else {
                    ((float*)Cp)[(size_t)row * N + col] = val + bias[col];
                }
            }
        }
    }
}

// qw[b,h] = sum_q bf2f(q_[b*14+q, h]) * wh[q]
__global__ __launch_bounds__(256)
void qw_reduce(const short* __restrict__ q_, const float* __restrict__ wh,
               float* __restrict__ qw)
{
    const int idx = blockIdx.x * 256 + threadIdx.x;
    const int b = idx >> 11;
    const int h = idx & 2047;
    float s = 0.0f;
    #pragma unroll
    for (int qq = 0; qq < 14; ++qq)
        s += bf2f(q_[(size_t)(b * 14 + qq) * 2048 + h]) * wh[qq];
    qw[idx] = s;
}

extern "C" void kernel_launch(void* const* d_in, const int* in_sizes, int n_in,
                              void* d_out, int out_size, void* d_ws, size_t ws_size,
                              hipStream_t stream)
{
    const float* v  = (const float*)d_in[0];
    const float* q  = (const float*)d_in[1];
    const float* Wv = (const float*)d_in[2];
    const float* bv = (const float*)d_in[3];
    const float* Wq = (const float*)d_in[4];
    const float* bq = (const float*)d_in[5];
    const float* wh = (const float*)d_in[6];
    const float* bh = (const float*)d_in[7];
    const float* W2 = (const float*)d_in[8];
    const float* b2 = (const float*)d_in[9];
    float* out = (float*)d_out;

    char* ws = (char*)d_ws;
    short* vb     = (short*)(ws);                  // 4608*2048*2 = 18,874,368
    short* Wvb    = (short*)(ws + 18874368);       // 2048*2048*2 =  8,388,608
    short* W2b    = (short*)(ws + 27262976);       // 2048*2048*2 =  8,388,608
    short* qb     = (short*)(ws + 35651584);       // 1792*1024*2 =  3,670,016
    short* Wqb    = (short*)(ws + 39321600);       // 2048*1024*2 =  4,194,304
    short* q_ws   = (short*)(ws + 43515904);       // 1792*2048*2 =  7,340,032
    float* qw     = (float*)(ws + 50855936);       // 128*2048*4  =  1,048,576
    short* logits = (short*)(ws + 51904512);       // 4608*2048*2 = 18,874,368
    // total: 70,778,880 B

    // C0: convert q, Wq (needed by K1) — one grid-stride pass
    cvt_qw<<<2048, 256, 0, stream>>>(q, qb, Wq, Wqb);

    // K1 fused: GEMM (224 blocks) + cvt of v/Wv/W2 (288 blocks)
    k1_fused<<<512, 256, 0, stream>>>(qb, Wqb, bq, q_ws,
                                      v, vb, Wv, Wvb, W2, W2b);

    // K2: qw reduce
    qw_reduce<<<(128 * 2048) / 256, 256, 0, stream>>>(q_ws, wh, qw);

    // K3: logits = relu(vb @ Wvb^T + bv) * qw + bh   M=4608, N=2048, K=2048
    gemm256<1><<<dim3(4608 / 256, 2048 / 256), 512, 0, stream>>>(
        vb, Wvb, bv, qw, bh, logits, 4608, 2048, 2048);

    // K4: out = logits @ W2b^T + b2   M=4608, N=2048, K=2048
    gemm256<2><<<dim3(4608 / 256, 2048 / 256), 512, 0, stream>>>(
        logits, W2b, b2, nullptr, nullptr, out, 4608, 2048, 2048);
}

// Round 16
// 119.789 us; speedup vs baseline: 1.4150x; 1.1713x over previous
//
#include <hip/hip_runtime.h>
#include <hip/hip_bf16.h>

// BCNet fused pipeline, MI355X gfx950 — round 16.
// gemm256 -> BM=192 x BN=256 (grid 24x8 = 192 blocks, 75% CU fill vs 56%).
// A-unit staged PADDED to 128 lds-rows (rows>=96 clamp to row0, never read) so
// the stage-call count, vmcnt ledger, phases, barriers and 128 KiB LDS are
// byte-identical to the proven 256² template. Readers touch only the 96 real
// rows (2 blocks x 48-row quadrant-halves); acc shrinks to [6][4].
//   C0: cvt_qw  q,Wq f32->bf16
//   K1f: blocks 0-223: q_ = relu(qb @ Wqb^T + bq); blocks 224-511: cvt v,Wv,W2
//   K2: qw[128,2048] = sum_q q_[b*14+q,:] * wh[q]
//   K3: logits = relu(vb @ Wvb^T + bv) * qw + bh       (192x256 8-phase)
//   K4: out = logits @ W2b^T + b2                      (192x256 8-phase)

typedef __attribute__((ext_vector_type(4))) float f32x4;
typedef __attribute__((ext_vector_type(8))) short short8;

__device__ __forceinline__ short f2bf(float f) {
    union { float f; unsigned u; } x; x.f = f;
    unsigned u = x.u;
    unsigned r = (u + 0x7FFFu + ((u >> 16) & 1u)) >> 16;   // RN-even
    return (short)(r & 0xFFFFu);
}
__device__ __forceinline__ float bf2f(short s) {
    union { unsigned u; float f; } x; x.u = ((unsigned)(unsigned short)s) << 16;
    return x.f;
}

__device__ __forceinline__ void gload_lds16(const short* g, short* l) {
    __builtin_amdgcn_global_load_lds(
        (const __attribute__((address_space(1))) unsigned int*)g,
        (__attribute__((address_space(3))) unsigned int*)l,
        16, 0, 0);
}

__device__ __forceinline__ void cvt_chunk(const float* __restrict__ src,
                                          short* __restrict__ dst, int i)
{
    f32x4 a = *(const f32x4*)&src[i];
    f32x4 b = *(const f32x4*)&src[i + 4];
    short8 s;
    #pragma unroll
    for (int j = 0; j < 4; ++j) { s[j] = f2bf(a[j]); s[4 + j] = f2bf(b[j]); }
    *(short8*)&dst[i] = s;
}

// ---------------- cvt of q, Wq (must precede K1) ----------------
#define Q_CH  229376                  // 1792*1024/8
#define QW_CH 262144                  // 2048*1024/8
__global__ __launch_bounds__(256)
void cvt_qw(const float* __restrict__ q,  short* __restrict__ qb,
            const float* __restrict__ Wq, short* __restrict__ Wqb)
{
    const int total = Q_CH + QW_CH;
    const int stride = gridDim.x * 256;
    for (int c = blockIdx.x * 256 + threadIdx.x; c < total; c += stride) {
        if (c < Q_CH) cvt_chunk(q, qb, c * 8);
        else          cvt_chunk(Wq, Wqb, (c - Q_CH) * 8);
    }
}

// ---------------- K1 fused: 128² BK=64 GEMM (blocks 0..223) + cvt (224..511) ----------------
#define V_CH  1179648                 // 4608*2048/8
#define WV_CH 524288                  // 2048*2048/8
#define W2_CH 524288
__global__ __launch_bounds__(256)
void k1_fused(const short* __restrict__ Ab, const short* __restrict__ Bb,
              const float* __restrict__ bias, short* __restrict__ Cp,
              const float* __restrict__ v,  short* __restrict__ vb,
              const float* __restrict__ Wv, short* __restrict__ Wvb,
              const float* __restrict__ W2, short* __restrict__ W2b)
{
    __shared__ short ldsA[128 * 64];
    __shared__ short ldsB[128 * 64];

    if (blockIdx.x >= 224) {
        const int total = V_CH + WV_CH + W2_CH;
        const int stride = 288 * 256;
        for (int c = (blockIdx.x - 224) * 256 + threadIdx.x; c < total; c += stride) {
            if      (c < V_CH)         cvt_chunk(v,  vb,  c * 8);
            else if (c < V_CH + WV_CH) cvt_chunk(Wv, Wvb, (c - V_CH) * 8);
            else                       cvt_chunk(W2, W2b, (c - V_CH - WV_CH) * 8);
        }
        return;
    }

    const int K = 1024, N = 2048;
    const int tid    = threadIdx.x;
    const int lane   = tid & 63;
    const int wid    = tid >> 6;
    const int wr     = wid >> 1;
    const int wc     = wid & 1;
    const int lrow   = lane & 15;
    const int lchunk = lane >> 4;

    const int row0 = (blockIdx.x % 14) * 128;
    const int col0 = (blockIdx.x / 14) * 128;

    const int s_r = lane >> 3;
    const int s_c = ((lane & 7) ^ s_r) * 8;

    f32x4 acc[4][4];
    #pragma unroll
    for (int i = 0; i < 4; ++i)
        #pragma unroll
        for (int j = 0; j < 4; ++j)
            acc[i][j] = (f32x4)0.0f;

    const int nk = K >> 6;

    for (int kt = 0; kt < nk; ++kt) {
        const int kc = kt * 64;
        if (kt) __syncthreads();
        #pragma unroll
        for (int i = 0; i < 4; ++i) {
            const int r = wid * 32 + i * 8 + s_r;
            gload_lds16(&Ab[(size_t)(row0 + r) * K + kc + s_c],
                        &ldsA[(wid * 32 + i * 8) * 64]);
            gload_lds16(&Bb[(size_t)(col0 + r) * K + kc + s_c],
                        &ldsB[(wid * 32 + i * 8) * 64]);
        }
        __syncthreads();

        short8 af[4][2], bfv[4][2];
        #pragma unroll
        for (int mi = 0; mi < 4; ++mi) {
            const int row = wr * 64 + mi * 16 + lrow;
            #pragma unroll
            for (int ks = 0; ks < 2; ++ks)
                af[mi][ks] = *(const short8*)((const char*)ldsA +
                    row * 128 + (((ks * 4 + lchunk) * 16) ^ ((row & 7) << 4)));
        }
        #pragma unroll
        for (int ni = 0; ni < 4; ++ni) {
            const int row = wc * 64 + ni * 16 + lrow;
            #pragma unroll
            for (int ks = 0; ks < 2; ++ks)
                bfv[ni][ks] = *(const short8*)((const char*)ldsB +
                    row * 128 + (((ks * 4 + lchunk) * 16) ^ ((row & 7) << 4)));
        }
        #pragma unroll
        for (int ks = 0; ks < 2; ++ks)
            #pragma unroll
            for (int mi = 0; mi < 4; ++mi)
                #pragma unroll
                for (int ni = 0; ni < 4; ++ni)
                    acc[mi][ni] = __builtin_amdgcn_mfma_f32_16x16x32_bf16(
                        af[mi][ks], bfv[ni][ks], acc[mi][ni], 0, 0, 0);
    }

    #pragma unroll
    for (int mi = 0; mi < 4; ++mi)
        #pragma unroll
        for (int ni = 0; ni < 4; ++ni)
            #pragma unroll
            for (int r = 0; r < 4; ++r) {
                const int row = row0 + wr * 64 + mi * 16 + lchunk * 4 + r;
                const int col = col0 + wc * 64 + ni * 16 + lrow;
                float val = fmaxf(acc[mi][ni][r] + bias[col], 0.0f);
                Cp[(size_t)row * N + col] = f2bf(val);
            }
}

// ---------------- 192x256 8-phase pipelined GEMM (K3/K4) ----------------
// EPI: 1 = relu(acc+bias[n]) * qw[row/36, n] + bh -> bf16
//      2 = acc + bias[n]                          -> f32
// BM=192: per-wave output 96x64; A units hold 96 real rows (2 blocks x 48)
// staged padded to 128 lds-rows. B path and entire schedule = proven template.
template<int EPI>
__global__ __launch_bounds__(512, 2)
void gemm256(const short* __restrict__ Ab, const short* __restrict__ Bb,
             const float* __restrict__ bias, const float* __restrict__ qw,
             const float* __restrict__ bh_p, void* __restrict__ Cp,
             int M, int N, int K)
{
    __shared__ short lds[2][4][128 * 64];   // [buf][Aq0,Aq1,Bq0,Bq1] = 128 KiB

    const int tid  = threadIdx.x;
    const int lane = tid & 63;
    const int w    = tid >> 6;     // 0..7
    const int wr   = w >> 2;       // 0..1
    const int wc   = w & 3;        // 0..3
    const int fr   = lane & 15;
    const int fc   = lane >> 4;

    const int row0 = blockIdx.x * 192;
    const int col0 = blockIdx.y * 256;

    const int sl_s = lane >> 3;                    // 0..7
    const int sl_c = ((lane & 7) ^ sl_s) * 8;      // pre-swizzled source col (shorts)

    const int nt = K >> 6;         // even, >= 4

    f32x4 acc[6][4];
    #pragma unroll
    for (int i = 0; i < 6; ++i)
        #pragma unroll
        for (int j = 0; j < 4; ++j)
            acc[i][j] = (f32x4)0.0f;

    // A-unit q: real rows = [block0 q-half 48][block1 q-half 48], lds-rows 96..127 pad.
    auto stageA = [&](int t, int q) {
        #pragma unroll
        for (int i = 0; i < 2; ++i) {
            const int g  = w * 2 + i;                  // 0..15
            const int rl = g * 8 + sl_s;               // 0..127 unit lds-row
            const int srow = (rl < 96)
                ? row0 + (rl / 48) * 96 + q * 48 + (rl % 48)
                : row0;                                 // pad, never read
            gload_lds16(&Ab[(size_t)srow * K + t * 64 + sl_c],
                        &lds[t & 1][q][g * 512]);
        }
    };
    auto stageB = [&](int t, int q) {
        #pragma unroll
        for (int i = 0; i < 2; ++i) {
            const int g  = w * 2 + i;
            const int rl = g * 8 + sl_s;
            const int srow = col0 + (rl >> 5) * 64 + q * 32 + (rl & 31);
            gload_lds16(&Bb[(size_t)srow * K + t * 64 + sl_c],
                        &lds[t & 1][2 + q][g * 512]);
        }
    };

    short8 A0[3][2], A1[3][2], B0[2][2], B1[2][2];

#define READA(T, MQ, DST)                                                       \
    _Pragma("unroll") for (int m_ = 0; m_ < 3; ++m_) {                          \
        const int rl_ = wr * 48 + m_ * 16 + fr;                                 \
        _Pragma("unroll") for (int k_ = 0; k_ < 2; ++k_)                        \
            DST[m_][k_] = *(const short8*)((const char*)&lds[(T) & 1][MQ][0]    \
                + rl_ * 128 + ((k_ * 64 + fc * 16) ^ ((rl_ & 7) << 4)));        \
    }
#define READB(T, NQ, DST)                                                       \
    _Pragma("unroll") for (int n_ = 0; n_ < 2; ++n_) {                          \
        const int rl_ = wc * 32 + n_ * 16 + fr;                                 \
        _Pragma("unroll") for (int k_ = 0; k_ < 2; ++k_)                        \
            DST[n_][k_] = *(const short8*)((const char*)&lds[(T) & 1][2 + (NQ)][0] \
                + rl_ * 128 + ((k_ * 64 + fc * 16) ^ ((rl_ & 7) << 4)));        \
    }
#define MFMAQ(MQ, NQ, ASET, BSET)                                               \
    _Pragma("unroll") for (int m_ = 0; m_ < 3; ++m_)                            \
      _Pragma("unroll") for (int n_ = 0; n_ < 2; ++n_)                          \
        _Pragma("unroll") for (int k_ = 0; k_ < 2; ++k_)                        \
          acc[(MQ) * 3 + m_][(NQ) * 2 + n_] =                                   \
              __builtin_amdgcn_mfma_f32_16x16x32_bf16(                          \
                  ASET[m_][k_], BSET[n_][k_], acc[(MQ) * 3 + m_][(NQ) * 2 + n_], 0, 0, 0);

#define BAR()   asm volatile("s_barrier" ::: "memory")
#define PRIO1() __builtin_amdgcn_s_setprio(1)
#define PRIO0() __builtin_amdgcn_s_setprio(0)
#define VM4()   asm volatile("s_waitcnt vmcnt(4)" ::: "memory")
#define VM0()   asm volatile("s_waitcnt vmcnt(0)" ::: "memory")

#define KITER(T0, T1, ST1, ST2, ST3, ST4, ST5, ST6, ST7, ST8, D4, D8)           \
  {                                                                             \
    READA(T0, 0, A0); READB(T0, 0, B0);                                         \
    PRIO1(); MFMAQ(0, 0, A0, B0); PRIO0();                                      \
    READB(T0, 1, B1); ST1; BAR();                                               \
    PRIO1(); MFMAQ(0, 1, A0, B1); PRIO0();                                      \
    READA(T0, 1, A1); ST2; BAR();                                               \
    PRIO1(); MFMAQ(1, 1, A1, B1); PRIO0();                                      \
    ST3; BAR();                                                                 \
    PRIO1(); MFMAQ(1, 0, A1, B0); PRIO0();                                      \
    ST4; D4; BAR();                                                             \
    READA(T1, 0, A0); READB(T1, 0, B0);                                         \
    PRIO1(); MFMAQ(0, 0, A0, B0); PRIO0();                                      \
    READB(T1, 1, B1); ST5; BAR();                                               \
    PRIO1(); MFMAQ(0, 1, A0, B1); PRIO0();                                      \
    READA(T1, 1, A1); ST6; BAR();                                               \
    PRIO1(); MFMAQ(1, 1, A1, B1); PRIO0();                                      \
    ST7; BAR();                                                                 \
    PRIO1(); MFMAQ(1, 0, A1, B0); PRIO0();                                      \
    ST8; D8; BAR();                                                             \
  }

    // prologue: T0 fully + Aq0(T1) + Bq1(T1); drain to T0-complete
    stageA(0, 0); stageB(0, 0); stageB(0, 1); stageA(0, 1);
    stageA(1, 0); stageB(1, 1);
    VM4();
    BAR();

    const int niter = (nt >> 1) - 1;
    for (int j = 0; j < niter; ++j) {
        const int t0 = 2 * j, t1 = 2 * j + 1;
        KITER(t0, t1,
              stageA(t1, 1),     stageB(t1, 0),
              stageA(t0 + 2, 0), stageB(t0 + 2, 1),
              stageA(t0 + 2, 1), stageB(t0 + 2, 0),
              stageA(t1 + 2, 0), stageB(t1 + 2, 1),
              VM4(), VM4());
    }
    // tail iteration
    {
        const int t0 = nt - 2, t1 = nt - 1;
        KITER(t0, t1,
              stageA(t1, 1), stageB(t1, 0),
              (void)0, (void)0, (void)0, (void)0, (void)0, (void)0,
              VM0(), (void)0);
    }

#undef KITER
#undef READA
#undef READB
#undef MFMAQ
#undef BAR
#undef PRIO1
#undef PRIO0
#undef VM4
#undef VM0

    // epilogue: C/D layout col = lane&15, row = (lane>>4)*4 + reg
    // acc index m = MQ*3 + m_ -> row = row0 + wr*96 + m*16 + fc*4 + r
    const float bhv = (EPI == 1) ? bh_p[0] : 0.0f;
    #pragma unroll
    for (int m = 0; m < 6; ++m) {
        #pragma unroll
        for (int n = 0; n < 4; ++n) {
            #pragma unroll
            for (int r = 0; r < 4; ++r) {
                const int row = row0 + wr * 96 + m * 16 + fc * 4 + r;
                const int col = col0 + wc * 64 + n * 16 + fr;
                float val = acc[m][n][r];
                if (EPI == 1) {
                    val = fmaxf(val + bias[col], 0.0f);
                    const int b = row / 36;
                    val = val * qw[b * 2048 + col] + bhv;
                    ((short*)Cp)[(size_t)row * N + col] = f2bf(val);
                } else {
                    ((float*)Cp)[(size_t)row * N + col] = val + bias[col];
                }
            }
        }
    }
}

// qw[b,h] = sum_q bf2f(q_[b*14+q, h]) * wh[q]
__global__ __launch_bounds__(256)
void qw_reduce(const short* __restrict__ q_, const float* __restrict__ wh,
               float* __restrict__ qw)
{
    const int idx = blockIdx.x * 256 + threadIdx.x;
    const int b = idx >> 11;
    const int h = idx & 2047;
    float s = 0.0f;
    #pragma unroll
    for (int qq = 0; qq < 14; ++qq)
        s += bf2f(q_[(size_t)(b * 14 + qq) * 2048 + h]) * wh[qq];
    qw[idx] = s;
}

extern "C" void kernel_launch(void* const* d_in, const int* in_sizes, int n_in,
                              void* d_out, int out_size, void* d_ws, size_t ws_size,
                              hipStream_t stream)
{
    const float* v  = (const float*)d_in[0];
    const float* q  = (const float*)d_in[1];
    const float* Wv = (const float*)d_in[2];
    const float* bv = (const float*)d_in[3];
    const float* Wq = (const float*)d_in[4];
    const float* bq = (const float*)d_in[5];
    const float* wh = (const float*)d_in[6];
    const float* bh = (const float*)d_in[7];
    const float* W2 = (const float*)d_in[8];
    const float* b2 = (const float*)d_in[9];
    float* out = (float*)d_out;

    char* ws = (char*)d_ws;
    short* vb     = (short*)(ws);                  // 4608*2048*2 = 18,874,368
    short* Wvb    = (short*)(ws + 18874368);       // 2048*2048*2 =  8,388,608
    short* W2b    = (short*)(ws + 27262976);       // 2048*2048*2 =  8,388,608
    short* qb     = (short*)(ws + 35651584);       // 1792*1024*2 =  3,670,016
    short* Wqb    = (short*)(ws + 39321600);       // 2048*1024*2 =  4,194,304
    short* q_ws   = (short*)(ws + 43515904);       // 1792*2048*2 =  7,340,032
    float* qw     = (float*)(ws + 50855936);       // 128*2048*4  =  1,048,576
    short* logits = (short*)(ws + 51904512);       // 4608*2048*2 = 18,874,368
    // total: 70,778,880 B

    // C0: convert q, Wq (needed by K1)
    cvt_qw<<<2048, 256, 0, stream>>>(q, qb, Wq, Wqb);

    // K1 fused: GEMM (224 blocks) + cvt of v/Wv/W2 (288 blocks)
    k1_fused<<<512, 256, 0, stream>>>(qb, Wqb, bq, q_ws,
                                      v, vb, Wv, Wvb, W2, W2b);

    // K2: qw reduce
    qw_reduce<<<(128 * 2048) / 256, 256, 0, stream>>>(q_ws, wh, qw);

    // K3: logits = relu(vb @ Wvb^T + bv) * qw + bh   M=4608, N=2048, K=2048
    gemm256<1><<<dim3(4608 / 192, 2048 / 256), 512, 0, stream>>>(
        vb, Wvb, bv, qw, bh, logits, 4608, 2048, 2048);

    // K4: out = logits @ W2b^T + b2   M=4608, N=2048, K=2048
    gemm256<2><<<dim3(4608 / 192, 2048 / 256), 512, 0, stream>>>(
        logits, W2b, b2, nullptr, nullptr, out, 4608, 2048, 2048);
}